// Round 6
// baseline (252.233 us; speedup 1.0000x reference)
//
#include <hip/hip_runtime.h>
#include <hip/hip_bf16.h>
#include <stdint.h>

#define NSH 256
#define AG 512          // alpha grid
#define BG 252          // beta grid
#define AB (AG*BG)      // 129024
#define KK 1024
#define DEPTH 16        // gemv pipeline depth (outstanding loads per wave)
#define SENT 0xFFFFFFFFFFFFFFFFull

// monotone float->uint map: ascending uint == ascending float
static __device__ __forceinline__ unsigned int fkey(float v){
    unsigned int u = __float_as_uint(v);
    u ^= (u >> 31) ? 0xFFFFFFFFu : 0x80000000u;
    return u;
}

#define GLOAD_LDS(gp, lp) __builtin_amdgcn_global_load_lds( \
    (__attribute__((address_space(1))) void*)(gp), \
    (__attribute__((address_space(3))) void*)(lp), 16, 0, 0)

// ---------------- GEMV: f[j] = sum_i sig[i]*sh[i*AB+j], sequential FMA i=0..255
// 16-deep per-wave-private global->LDS pipeline with counted vmcnt (never 0).
// Each wave stages & consumes its own 1KB slice per row: NO barriers in loop.
__global__ __launch_bounds__(256) void k_gemv(const float* __restrict__ sig,
        const float* __restrict__ sh1, const float* __restrict__ sh2,
        float* __restrict__ f, unsigned int* __restrict__ counts){
    __shared__ float sig_s[NSH];
    __shared__ float tile[DEPTH][1024];
    int tid = threadIdx.x;
    if (blockIdx.x == 0 && blockIdx.y == 0 && tid < 2) counts[tid] = 0;
    sig_s[tid] = sig[tid];
    __syncthreads();
    int proj = blockIdx.y;
    const float* sh = proj ? sh2 : sh1;
    int jbase = blockIdx.x * 1024;
    int wave = tid >> 6, lane = tid & 63;
    int wslot = wave * 256 + lane * 4;          // float index inside a 1024-row-slice
    const float* gsrc = sh + jbase + wslot;     // per-lane global src (HW takes per-lane addr)
    // prologue: fill the pipe (rows 0..DEPTH-1)
    #pragma unroll
    for (int ipf = 0; ipf < DEPTH; ++ipf)
        GLOAD_LDS(gsrc + (size_t)ipf * AB, &tile[ipf][wave * 256]);
    float a0 = 0.f, a1 = 0.f, a2 = 0.f, a3 = 0.f;
    for (int i = 0; i < NSH; ++i){
        asm volatile("s_waitcnt vmcnt(15)" ::: "memory");   // row i landed; 15 in flight
        float4 v = *reinterpret_cast<const float4*>(&tile[i & (DEPTH-1)][wslot]);
        float si = sig_s[i];
        int pf = i + DEPTH; pf = pf > NSH - 1 ? NSH - 1 : pf;   // clamp keeps vmcnt exact
        GLOAD_LDS(gsrc + (size_t)pf * AB, &tile[i & (DEPTH-1)][wave * 256]);
        a0 = fmaf(si, v.x, a0);
        a1 = fmaf(si, v.y, a1);
        a2 = fmaf(si, v.z, a2);
        a3 = fmaf(si, v.w, a3);
    }
    float4 o; o.x = a0; o.y = a1; o.z = a2; o.w = a3;
    *reinterpret_cast<float4*>(f + (size_t)proj * AB + jbase + wslot) = o;
}

// ---------------- mask + pack candidate keys (wave-aggregated atomics)
__global__ __launch_bounds__(256) void k_mask(const float* __restrict__ f,
        unsigned long long* __restrict__ cand, unsigned int* __restrict__ counts){
    int proj = blockIdx.y;
    const float* fp = f + (size_t)proj * AB;
    int j = blockIdx.x * 256 + threadIdx.x;
    bool pred = false;
    unsigned long long key = 0;
    {
        int a = j / BG, b = j - a * BG;
        if (a > 0 && a < AG - 1 && b > 0 && b < BG - 1){
            float v = fp[j];
            pred = (v > fp[j-1]) && (v > fp[j+1]) && (v > fp[j-BG]) && (v > fp[j+BG]);
            if (pred)
                key = (((unsigned long long)(~fkey(v))) << 32) | (unsigned int)j;
        }
    }
    unsigned long long bal = __ballot(pred);
    if (bal){
        int lane = threadIdx.x & 63;
        int leader = __ffsll(bal) - 1;
        unsigned int base = 0;
        if (lane == leader) base = atomicAdd(&counts[proj], (unsigned int)__popcll(bal));
        base = __shfl(base, leader);
        if (pred){
            unsigned int off = (unsigned int)__popcll(bal & ((1ull << lane) - 1ull));
            cand[(size_t)proj * AB + base + off] = key;
        }
    }
}

// ---------------- single-block radix-select of K smallest 64-bit keys
// bin choice is wave-parallel (shfl scan) -- no serial 256-bin walk.
__global__ __launch_bounds__(1024) void k_select(const unsigned long long* __restrict__ cand,
        const unsigned int* __restrict__ counts, unsigned long long* __restrict__ sel){
    int proj = blockIdx.y;
    const unsigned long long* cp = cand + (size_t)proj * AB;
    unsigned long long* sp = sel + proj * KK;
    unsigned int count = counts[proj];
    int tid = threadIdx.x;
    if (count <= KK){
        if (tid < KK) sp[tid] = SENT;               // pad
        if (tid < (int)count) sp[tid] = cp[tid];    // same thread overwrites same slot
        return;
    }
    __shared__ unsigned int hist[256];
    __shared__ unsigned int sbin, sremk;
    unsigned long long prefix = 0, pmask = 0;
    unsigned int remk = KK;
    for (int lvl = 7; lvl >= 0; --lvl){
        int shft = lvl * 8;
        if (tid < 256) hist[tid] = 0;
        __syncthreads();
        for (unsigned int i = tid; i < count; i += 1024){
            unsigned long long k = cp[i];
            if ((k & pmask) == prefix)
                atomicAdd(&hist[(unsigned int)(k >> shft) & 255u], 1u);
        }
        __syncthreads();
        if (tid < 64){
            unsigned int b0 = hist[tid*4+0], b1 = hist[tid*4+1];
            unsigned int b2 = hist[tid*4+2], b3 = hist[tid*4+3];
            unsigned int lsum = b0 + b1 + b2 + b3;
            unsigned int incl = lsum;
            #pragma unroll
            for (int off = 1; off < 64; off <<= 1){
                unsigned int v = __shfl_up(incl, off);
                if (tid >= off) incl += v;
            }
            unsigned int excl = incl - lsum;
            if (excl < remk && remk <= incl){
                unsigned int r = remk - excl;          // 1-based within this lane's 4 bins
                unsigned int c0 = b0, c01 = b0 + b1, c012 = b0 + b1 + b2;
                unsigned int bin, rr;
                if (r <= c0){ bin = tid*4+0; rr = r; }
                else if (r <= c01){ bin = tid*4+1; rr = r - c0; }
                else if (r <= c012){ bin = tid*4+2; rr = r - c01; }
                else { bin = tid*4+3; rr = r - c012; }
                sbin = bin; sremk = rr;
            }
        }
        __syncthreads();
        prefix |= ((unsigned long long)sbin) << shft;
        pmask  |= 0xFFull << shft;
        remk = sremk;
        __syncthreads();
    }
    // prefix == K-th smallest key (keys unique: value bits + index)
    __shared__ unsigned int pos;
    if (tid == 0) pos = 0;
    __syncthreads();
    for (unsigned int i = tid; i < count; i += 1024){
        unsigned long long k = cp[i];
        if (k <= prefix){
            unsigned int p = atomicAdd(&pos, 1u);
            sp[p] = k;
        }
    }
}

// ---------------- bitonic sort 1024 keys + gather peaks/radius/valid
__global__ __launch_bounds__(1024) void k_sortgather(const unsigned long long* __restrict__ sel,
        const float* __restrict__ f, const float* __restrict__ xyz1,
        const float* __restrict__ xyz2, float4* __restrict__ pr,
        unsigned int* __restrict__ vb, float* __restrict__ out){
    int proj = blockIdx.y;
    int tid = threadIdx.x;
    __shared__ unsigned long long s[KK];
    s[tid] = sel[proj * KK + tid];
    __syncthreads();
    for (int k = 2; k <= KK; k <<= 1){
        for (int j = k >> 1; j > 0; j >>= 1){
            int ixj = tid ^ j;
            if (ixj > tid){
                unsigned long long a = s[tid], b = s[ixj];
                bool asc = (tid & k) == 0;
                if ((a > b) == asc){ s[tid] = b; s[ixj] = a; }
            }
            __syncthreads();
        }
    }
    unsigned long long key = s[tid];
    bool val = (key != SENT);
    unsigned int j = (unsigned int)key;
    const float* fp = f + (size_t)proj * AB;
    const float* xyz = proj ? xyz2 : xyz1;
    float4 o = make_float4(0.f, 0.f, 0.f, 0.f);
    if (val){
        o.x = xyz[(size_t)j * 3 + 0];
        o.y = xyz[(size_t)j * 3 + 1];
        o.z = xyz[(size_t)j * 3 + 2];
        o.w = fp[j];                    // radius
    }
    pr[proj * KK + tid] = o;
    vb[proj * KK + tid] = val ? 1u : 0u;
    if (proj == 1){
        int row = KK + tid;
        out[row * 3 + 0] = o.x;
        out[row * 3 + 1] = o.y;
        out[row * 3 + 2] = o.z;
        out[2 * KK * 3 + row] = o.w;            // radius block at 6144
        out[2 * KK * 3 + 2 * KK + row] = val ? 1.0f : 0.0f;  // valid block at 8192
    }
}

// ---------------- dedup (single pass): each block tests 256 p1-peaks vs all 1024 p2,
// writes output rows 0..1023 directly. Branchless; invalid p2 -> far sentinel.
__global__ __launch_bounds__(256) void k_dedup(const float4* __restrict__ pr,
        const unsigned int* __restrict__ vb, float* __restrict__ out){
    const float THRF = (float)(6.283185307179586 / 256.0);
    int tid = threadIdx.x;
    __shared__ float sx[KK], sy[KK], sz[KK];
    #pragma unroll
    for (int t = 0; t < 4; ++t){
        int idx = t * 256 + tid;
        float4 v = pr[KK + idx];
        bool v2 = vb[KK + idx] != 0;
        sx[idx] = v2 ? v.x : 1e9f;
        sy[idx] = v2 ? v.y : 1e9f;
        sz[idx] = v2 ? v.z : 1e9f;
    }
    __syncthreads();
    int k = blockIdx.x * 256 + tid;
    float4 m = pr[k];
    bool close = false;
    {
        #pragma clang fp contract(off)
        #pragma unroll 8
        for (int jj = 0; jj < KK; ++jj){
            float dx = m.x - sx[jj];
            float dy = m.y - sy[jj];
            float dz = m.z - sz[jj];
            float d2 = dx * dx + dy * dy + dz * dz;
            close = close | (sqrtf(d2) < THRF);
        }
    }
    bool keep = (vb[k] != 0) && !close;
    out[k * 3 + 0] = keep ? m.x : 0.0f;
    out[k * 3 + 1] = keep ? m.y : 0.0f;
    out[k * 3 + 2] = keep ? m.z : 0.0f;
    out[2 * KK * 3 + k] = keep ? m.w : 0.0f;                 // radius block
    out[2 * KK * 3 + 2 * KK + k] = keep ? 1.0f : 0.0f;       // valid block
}

extern "C" void kernel_launch(void* const* d_in, const int* in_sizes, int n_in,
                              void* d_out, int out_size, void* d_ws, size_t ws_size,
                              hipStream_t stream){
    const float* sig  = (const float*)d_in[0];
    const float* sh1  = (const float*)d_in[1];
    const float* sh2  = (const float*)d_in[2];
    const float* xyz1 = (const float*)d_in[3];
    const float* xyz2 = (const float*)d_in[4];
    float* out = (float*)d_out;
    char* ws = (char*)d_ws;

    // workspace layout (~3.3 MB)
    float* f                  = (float*)(ws);                         // 2*AB*4
    unsigned long long* cand  = (unsigned long long*)(ws + 0x100000); // 2*AB*8
    unsigned int* counts      = (unsigned int*)(ws + 0x300000);       // 8 B
    unsigned long long* sel   = (unsigned long long*)(ws + 0x300100); // 16 KB
    float4* pr                = (float4*)(ws + 0x310000);             // 32 KB
    unsigned int* vb          = (unsigned int*)(ws + 0x320000);       // 8 KB

    k_gemv<<<dim3(AB / 1024, 2), dim3(256), 0, stream>>>(sig, sh1, sh2, f, counts);
    k_mask<<<dim3(AB / 256, 2), dim3(256), 0, stream>>>(f, cand, counts);
    k_select<<<dim3(1, 2), dim3(1024), 0, stream>>>(cand, counts, sel);
    k_sortgather<<<dim3(1, 2), dim3(1024), 0, stream>>>(sel, f, xyz1, xyz2, pr, vb, out);
    k_dedup<<<dim3(4, 1), dim3(256), 0, stream>>>(pr, vb, out);
}

// Round 7
// 214.865 us; speedup vs baseline: 1.1739x; 1.1739x over previous
//
#include <hip/hip_runtime.h>
#include <hip/hip_bf16.h>
#include <stdint.h>

#define NSH 256
#define AG 512          // alpha grid
#define BG 252          // beta grid
#define AB (AG*BG)      // 129024
#define KK 1024
#define SENT 0xFFFFFFFFFFFFFFFFull

// monotone float->uint map: ascending uint == ascending float
static __device__ __forceinline__ unsigned int fkey(float v){
    unsigned int u = __float_as_uint(v);
    u ^= (u >> 31) ? 0xFFFFFFFFu : 0x80000000u;
    return u;
}

// ---------------- GEMV: f[j] = sum_i sig[i]*sh[i*AB+j], sequential FMA i=0..255
// 16-chunk structure: burst-issue 16 independent float4 loads (64 VGPRs live),
// sched_barrier(0) pins them above the consume phase -> ~16KB in flight/wave.
__global__ __launch_bounds__(256) void k_gemv(const float* __restrict__ sig,
        const float* __restrict__ sh1, const float* __restrict__ sh2,
        float* __restrict__ f, unsigned int* __restrict__ counts){
    __shared__ float sig_s[NSH];
    int tid = threadIdx.x;
    if (blockIdx.x == 0 && blockIdx.y == 0 && tid < 2) counts[tid] = 0;
    sig_s[tid] = sig[tid];
    __syncthreads();
    int proj = blockIdx.y;
    const float* sh = proj ? sh2 : sh1;
    size_t j4 = ((size_t)blockIdx.x * 256 + tid) * 4;
    const float* p = sh + j4;
    float a0 = 0.f, a1 = 0.f, a2 = 0.f, a3 = 0.f;
    float4 buf[16];
    for (int c = 0; c < NSH; c += 16){
        #pragma unroll
        for (int u = 0; u < 16; ++u)
            buf[u] = *reinterpret_cast<const float4*>(p + (size_t)(c + u) * AB);
        __builtin_amdgcn_sched_barrier(0);   // forbid sinking loads below this point
        #pragma unroll
        for (int u = 0; u < 16; ++u){
            float si = sig_s[c + u];
            a0 = fmaf(si, buf[u].x, a0);
            a1 = fmaf(si, buf[u].y, a1);
            a2 = fmaf(si, buf[u].z, a2);
            a3 = fmaf(si, buf[u].w, a3);
        }
        __builtin_amdgcn_sched_barrier(0);   // forbid hoisting next burst into consume
    }
    float4 o; o.x = a0; o.y = a1; o.z = a2; o.w = a3;
    *reinterpret_cast<float4*>(f + (size_t)proj * AB + j4) = o;
}

// ---------------- mask + pack candidate keys (wave-aggregated atomics)
__global__ __launch_bounds__(256) void k_mask(const float* __restrict__ f,
        unsigned long long* __restrict__ cand, unsigned int* __restrict__ counts){
    int proj = blockIdx.y;
    const float* fp = f + (size_t)proj * AB;
    int j = blockIdx.x * 256 + threadIdx.x;
    bool pred = false;
    unsigned long long key = 0;
    {
        int a = j / BG, b = j - a * BG;
        if (a > 0 && a < AG - 1 && b > 0 && b < BG - 1){
            float v = fp[j];
            pred = (v > fp[j-1]) && (v > fp[j+1]) && (v > fp[j-BG]) && (v > fp[j+BG]);
            if (pred)
                key = (((unsigned long long)(~fkey(v))) << 32) | (unsigned int)j;
        }
    }
    unsigned long long bal = __ballot(pred);
    if (bal){
        int lane = threadIdx.x & 63;
        int leader = __ffsll(bal) - 1;
        unsigned int base = 0;
        if (lane == leader) base = atomicAdd(&counts[proj], (unsigned int)__popcll(bal));
        base = __shfl(base, leader);
        if (pred){
            unsigned int off = (unsigned int)__popcll(bal & ((1ull << lane) - 1ull));
            cand[(size_t)proj * AB + base + off] = key;
        }
    }
}

// ---------------- single-block radix-select of K smallest 64-bit keys
// bin choice is wave-parallel (shfl scan) -- no serial 256-bin walk.
__global__ __launch_bounds__(1024) void k_select(const unsigned long long* __restrict__ cand,
        const unsigned int* __restrict__ counts, unsigned long long* __restrict__ sel){
    int proj = blockIdx.y;
    const unsigned long long* cp = cand + (size_t)proj * AB;
    unsigned long long* sp = sel + proj * KK;
    unsigned int count = counts[proj];
    int tid = threadIdx.x;
    if (count <= KK){
        if (tid < KK) sp[tid] = SENT;               // pad
        if (tid < (int)count) sp[tid] = cp[tid];    // same thread overwrites same slot
        return;
    }
    __shared__ unsigned int hist[256];
    __shared__ unsigned int sbin, sremk;
    unsigned long long prefix = 0, pmask = 0;
    unsigned int remk = KK;
    for (int lvl = 7; lvl >= 0; --lvl){
        int shft = lvl * 8;
        if (tid < 256) hist[tid] = 0;
        __syncthreads();
        for (unsigned int i = tid; i < count; i += 1024){
            unsigned long long k = cp[i];
            if ((k & pmask) == prefix)
                atomicAdd(&hist[(unsigned int)(k >> shft) & 255u], 1u);
        }
        __syncthreads();
        if (tid < 64){
            unsigned int b0 = hist[tid*4+0], b1 = hist[tid*4+1];
            unsigned int b2 = hist[tid*4+2], b3 = hist[tid*4+3];
            unsigned int lsum = b0 + b1 + b2 + b3;
            unsigned int incl = lsum;
            #pragma unroll
            for (int off = 1; off < 64; off <<= 1){
                unsigned int v = __shfl_up(incl, off);
                if (tid >= off) incl += v;
            }
            unsigned int excl = incl - lsum;
            if (excl < remk && remk <= incl){
                unsigned int r = remk - excl;          // 1-based within this lane's 4 bins
                unsigned int c0 = b0, c01 = b0 + b1, c012 = b0 + b1 + b2;
                unsigned int bin, rr;
                if (r <= c0){ bin = tid*4+0; rr = r; }
                else if (r <= c01){ bin = tid*4+1; rr = r - c0; }
                else if (r <= c012){ bin = tid*4+2; rr = r - c01; }
                else { bin = tid*4+3; rr = r - c012; }
                sbin = bin; sremk = rr;
            }
        }
        __syncthreads();
        prefix |= ((unsigned long long)sbin) << shft;
        pmask  |= 0xFFull << shft;
        remk = sremk;
        __syncthreads();
    }
    // prefix == K-th smallest key (keys unique: value bits + index)
    __shared__ unsigned int pos;
    if (tid == 0) pos = 0;
    __syncthreads();
    for (unsigned int i = tid; i < count; i += 1024){
        unsigned long long k = cp[i];
        if (k <= prefix){
            unsigned int p = atomicAdd(&pos, 1u);
            sp[p] = k;
        }
    }
}

// ---------------- bitonic sort 1024 keys + gather peaks/radius/valid
__global__ __launch_bounds__(1024) void k_sortgather(const unsigned long long* __restrict__ sel,
        const float* __restrict__ f, const float* __restrict__ xyz1,
        const float* __restrict__ xyz2, float4* __restrict__ pr,
        unsigned int* __restrict__ vb, float* __restrict__ out){
    int proj = blockIdx.y;
    int tid = threadIdx.x;
    __shared__ unsigned long long s[KK];
    s[tid] = sel[proj * KK + tid];
    __syncthreads();
    for (int k = 2; k <= KK; k <<= 1){
        for (int j = k >> 1; j > 0; j >>= 1){
            int ixj = tid ^ j;
            if (ixj > tid){
                unsigned long long a = s[tid], b = s[ixj];
                bool asc = (tid & k) == 0;
                if ((a > b) == asc){ s[tid] = b; s[ixj] = a; }
            }
            __syncthreads();
        }
    }
    unsigned long long key = s[tid];
    bool val = (key != SENT);
    unsigned int j = (unsigned int)key;
    const float* fp = f + (size_t)proj * AB;
    const float* xyz = proj ? xyz2 : xyz1;
    float4 o = make_float4(0.f, 0.f, 0.f, 0.f);
    if (val){
        o.x = xyz[(size_t)j * 3 + 0];
        o.y = xyz[(size_t)j * 3 + 1];
        o.z = xyz[(size_t)j * 3 + 2];
        o.w = fp[j];                    // radius
    }
    pr[proj * KK + tid] = o;
    vb[proj * KK + tid] = val ? 1u : 0u;
    if (proj == 1){
        int row = KK + tid;
        out[row * 3 + 0] = o.x;
        out[row * 3 + 1] = o.y;
        out[row * 3 + 2] = o.z;
        out[2 * KK * 3 + row] = o.w;            // radius block at 6144
        out[2 * KK * 3 + 2 * KK + row] = val ? 1.0f : 0.0f;  // valid block at 8192
    }
}

// ---------------- dedup (single pass): each block tests 256 p1-peaks vs all 1024 p2,
// writes output rows 0..1023 directly. Branchless; invalid p2 -> far sentinel.
__global__ __launch_bounds__(256) void k_dedup(const float4* __restrict__ pr,
        const unsigned int* __restrict__ vb, float* __restrict__ out){
    const float THRF = (float)(6.283185307179586 / 256.0);
    int tid = threadIdx.x;
    __shared__ float sx[KK], sy[KK], sz[KK];
    #pragma unroll
    for (int t = 0; t < 4; ++t){
        int idx = t * 256 + tid;
        float4 v = pr[KK + idx];
        bool v2 = vb[KK + idx] != 0;
        sx[idx] = v2 ? v.x : 1e9f;
        sy[idx] = v2 ? v.y : 1e9f;
        sz[idx] = v2 ? v.z : 1e9f;
    }
    __syncthreads();
    int k = blockIdx.x * 256 + tid;
    float4 m = pr[k];
    bool close = false;
    {
        #pragma clang fp contract(off)
        #pragma unroll 8
        for (int jj = 0; jj < KK; ++jj){
            float dx = m.x - sx[jj];
            float dy = m.y - sy[jj];
            float dz = m.z - sz[jj];
            float d2 = dx * dx + dy * dy + dz * dz;
            close = close | (sqrtf(d2) < THRF);
        }
    }
    bool keep = (vb[k] != 0) && !close;
    out[k * 3 + 0] = keep ? m.x : 0.0f;
    out[k * 3 + 1] = keep ? m.y : 0.0f;
    out[k * 3 + 2] = keep ? m.z : 0.0f;
    out[2 * KK * 3 + k] = keep ? m.w : 0.0f;                 // radius block
    out[2 * KK * 3 + 2 * KK + k] = keep ? 1.0f : 0.0f;       // valid block
}

extern "C" void kernel_launch(void* const* d_in, const int* in_sizes, int n_in,
                              void* d_out, int out_size, void* d_ws, size_t ws_size,
                              hipStream_t stream){
    const float* sig  = (const float*)d_in[0];
    const float* sh1  = (const float*)d_in[1];
    const float* sh2  = (const float*)d_in[2];
    const float* xyz1 = (const float*)d_in[3];
    const float* xyz2 = (const float*)d_in[4];
    float* out = (float*)d_out;
    char* ws = (char*)d_ws;

    // workspace layout (~3.3 MB)
    float* f                  = (float*)(ws);                         // 2*AB*4
    unsigned long long* cand  = (unsigned long long*)(ws + 0x100000); // 2*AB*8
    unsigned int* counts      = (unsigned int*)(ws + 0x300000);       // 8 B
    unsigned long long* sel   = (unsigned long long*)(ws + 0x300100); // 16 KB
    float4* pr                = (float4*)(ws + 0x310000);             // 32 KB
    unsigned int* vb          = (unsigned int*)(ws + 0x320000);       // 8 KB

    k_gemv<<<dim3(AB / 1024, 2), dim3(256), 0, stream>>>(sig, sh1, sh2, f, counts);
    k_mask<<<dim3(AB / 256, 2), dim3(256), 0, stream>>>(f, cand, counts);
    k_select<<<dim3(1, 2), dim3(1024), 0, stream>>>(cand, counts, sel);
    k_sortgather<<<dim3(1, 2), dim3(1024), 0, stream>>>(sel, f, xyz1, xyz2, pr, vb, out);
    k_dedup<<<dim3(4, 1), dim3(256), 0, stream>>>(pr, vb, out);
}

// Round 11
// 195.639 us; speedup vs baseline: 1.2893x; 1.0983x over previous
//
#include <hip/hip_runtime.h>
#include <hip/hip_bf16.h>
#include <stdint.h>

#define NSH 256
#define AG 512          // alpha grid
#define BG 252          // beta grid
#define AB (AG*BG)      // 129024
#define KK 1024
#define DEPTH 16
#define SENT 0xFFFFFFFFFFFFFFFFull

typedef float f32x4 __attribute__((ext_vector_type(4)));
typedef __attribute__((address_space(3))) float lds_f;

// monotone float->uint map: ascending uint == ascending float
static __device__ __forceinline__ unsigned int fkey(float v){
    unsigned int u = __float_as_uint(v);
    u ^= (u >> 31) ? 0xFFFFFFFFu : 0x80000000u;
    return u;
}

#define GLOAD4(gp, lp) __builtin_amdgcn_global_load_lds( \
    (__attribute__((address_space(1))) void*)(gp), \
    (__attribute__((address_space(3))) void*)(lp), 4, 0, 0)

// ---------------- GEMV: f[j] = sum_i sig[i]*sh[i*AB+j], sequential FMA i=0..255
// Safe async pipeline: global_load_lds (no VGPR dest -> no regalloc hazard),
// counted vmcnt(DEPTH-1) + ds_read + lgkmcnt(0) fused in ONE asm block per step
// (output complete at asm end). 1 float/thread, 128-thr blocks -> 2016 blocks,
// ~16 waves/CU: TLP hides the serialized LDS-read latency; 64KB in flight/CU.
__global__ __launch_bounds__(128) void k_gemv(const float* __restrict__ sig,
        const float* __restrict__ sh1, const float* __restrict__ sh2,
        float* __restrict__ f, unsigned int* __restrict__ counts){
    __shared__ float sig_s[NSH];
    __shared__ float tile[DEPTH][128];
    int tid = threadIdx.x;
    if (blockIdx.x == 0 && blockIdx.y == 0 && tid < 2) counts[tid] = 0;
    sig_s[tid] = sig[tid];
    sig_s[tid + 128] = sig[tid + 128];
    __syncthreads();
    int proj = blockIdx.y;
    const float* shp = proj ? sh2 : sh1;
    int jbase = blockIdx.x * 128;
    int wave = tid >> 6;
    const float* gcol = shp + jbase + tid;              // per-lane column address (row 0)
    lds_f* wr0 = (lds_f*)&tile[0][wave * 64];           // wave-uniform LDS dest base
    lds_f* rd0 = (lds_f*)&tile[0][0] + tid;             // this thread's read slot
    lds_f* sg0 = (lds_f*)&sig_s[0];

    #pragma unroll
    for (int d = 0; d < DEPTH; ++d)
        GLOAD4(gcol + (size_t)d * AB, wr0 + d * 128);

    const float* gpf  = gcol + (size_t)DEPTH * AB;
    const float* gmax = gcol + (size_t)(NSH - 1) * AB;  // clamp keeps vmcnt exact
    float acc = 0.f;

#define GSTEP(u, sv) do{ \
        float v; \
        asm volatile("s_waitcnt vmcnt(15)\n\tds_read_b32 %0, %1\n\ts_waitcnt lgkmcnt(0)" \
            : "=v"(v) : "v"(rd0 + (u) * 128) : "memory"); \
        acc = fmaf(sv, v, acc); \
        const float* guse = gpf > gmax ? gmax : gpf; \
        GLOAD4(guse, wr0 + (u) * 128); \
        gpf += AB; \
    }while(0)

    for (int c = 0; c < 16; ++c){
        f32x4 s0, s1, s2, s3;   // 16 sig values for this chunk, read via one asm block
        asm volatile("ds_read_b128 %0, %4\n\t"
                     "ds_read_b128 %1, %4 offset:16\n\t"
                     "ds_read_b128 %2, %4 offset:32\n\t"
                     "ds_read_b128 %3, %4 offset:48\n\t"
                     "s_waitcnt lgkmcnt(0)"
            : "=v"(s0), "=v"(s1), "=v"(s2), "=v"(s3)
            : "v"(sg0 + c * 16) : "memory");
        GSTEP(0,  s0[0]); GSTEP(1,  s0[1]); GSTEP(2,  s0[2]); GSTEP(3,  s0[3]);
        GSTEP(4,  s1[0]); GSTEP(5,  s1[1]); GSTEP(6,  s1[2]); GSTEP(7,  s1[3]);
        GSTEP(8,  s2[0]); GSTEP(9,  s2[1]); GSTEP(10, s2[2]); GSTEP(11, s2[3]);
        GSTEP(12, s3[0]); GSTEP(13, s3[1]); GSTEP(14, s3[2]); GSTEP(15, s3[3]);
    }
#undef GSTEP

    asm volatile("s_waitcnt vmcnt(0)" ::: "memory");
    __builtin_amdgcn_sched_barrier(0);
    f[(size_t)proj * AB + jbase + tid] = acc;
}

// ---------------- mask + pack candidate keys (wave-aggregated atomics)
__global__ __launch_bounds__(256) void k_mask(const float* __restrict__ f,
        unsigned long long* __restrict__ cand, unsigned int* __restrict__ counts){
    int proj = blockIdx.y;
    const float* fp = f + (size_t)proj * AB;
    int j = blockIdx.x * 256 + threadIdx.x;
    bool pred = false;
    unsigned long long key = 0;
    {
        int a = j / BG, b = j - a * BG;
        if (a > 0 && a < AG - 1 && b > 0 && b < BG - 1){
            float v = fp[j];
            pred = (v > fp[j-1]) && (v > fp[j+1]) && (v > fp[j-BG]) && (v > fp[j+BG]);
            if (pred)
                key = (((unsigned long long)(~fkey(v))) << 32) | (unsigned int)j;
        }
    }
    unsigned long long bal = __ballot(pred);
    if (bal){
        int lane = threadIdx.x & 63;
        int leader = __ffsll(bal) - 1;
        unsigned int base = 0;
        if (lane == leader) base = atomicAdd(&counts[proj], (unsigned int)__popcll(bal));
        base = __shfl(base, leader);
        if (pred){
            unsigned int off = (unsigned int)__popcll(bal & ((1ull << lane) - 1ull));
            cand[(size_t)proj * AB + base + off] = key;
        }
    }
}

// ---------------- fused: radix-select (4 levels, value bits only) + bitonic sort
// + gather/write. Index tie-break at the cutoff value via tiny equal-value list.
__global__ __launch_bounds__(1024) void k_selsort(const unsigned long long* __restrict__ cand,
        const unsigned int* __restrict__ counts, const float* __restrict__ f,
        const float* __restrict__ xyz1, const float* __restrict__ xyz2,
        float4* __restrict__ pr, unsigned int* __restrict__ vb, float* __restrict__ out){
    int proj = blockIdx.y;
    const unsigned long long* cp = cand + (size_t)proj * AB;
    unsigned int count = counts[proj];
    int tid = threadIdx.x;
    __shared__ unsigned long long s[KK];
    __shared__ unsigned int hist[256];
    __shared__ unsigned int sbin, sremk, pos, eqn;
    __shared__ unsigned long long eq[256];

    if (count <= KK){
        s[tid] = (tid < (int)count) ? cp[tid] : SENT;
    } else {
        unsigned long long prefix = 0, pmask = 0;
        unsigned int remk = KK;
        for (int lvl = 7; lvl >= 4; --lvl){
            int shft = lvl * 8;
            if (tid < 256) hist[tid] = 0;
            __syncthreads();
            for (unsigned int i = tid; i < count; i += 1024){
                unsigned long long k = cp[i];
                if ((k & pmask) == prefix)
                    atomicAdd(&hist[(unsigned int)(k >> shft) & 255u], 1u);
            }
            __syncthreads();
            if (tid < 64){
                unsigned int b0 = hist[tid*4+0], b1 = hist[tid*4+1];
                unsigned int b2 = hist[tid*4+2], b3 = hist[tid*4+3];
                unsigned int lsum = b0 + b1 + b2 + b3;
                unsigned int incl = lsum;
                #pragma unroll
                for (int off = 1; off < 64; off <<= 1){
                    unsigned int v = __shfl_up(incl, off);
                    if (tid >= off) incl += v;
                }
                unsigned int excl = incl - lsum;
                if (excl < remk && remk <= incl){
                    unsigned int r = remk - excl;
                    unsigned int c0 = b0, c01 = b0 + b1, c012 = b0 + b1 + b2;
                    unsigned int bin, rr;
                    if (r <= c0){ bin = tid*4+0; rr = r; }
                    else if (r <= c01){ bin = tid*4+1; rr = r - c0; }
                    else if (r <= c012){ bin = tid*4+2; rr = r - c01; }
                    else { bin = tid*4+3; rr = r - c012; }
                    sbin = bin; sremk = rr;
                }
            }
            __syncthreads();
            prefix |= ((unsigned long long)sbin) << shft;
            pmask  |= 0xFFull << shft;
            remk = sremk;
            __syncthreads();
        }
        if (tid == 0){ pos = 0; eqn = 0; }
        __syncthreads();
        unsigned int cutv = (unsigned int)(prefix >> 32);
        for (unsigned int i = tid; i < count; i += 1024){
            unsigned long long k = cp[i];
            unsigned int hv = (unsigned int)(k >> 32);
            if (hv < cutv){ s[atomicAdd(&pos, 1u)] = k; }
            else if (hv == cutv){ unsigned e = atomicAdd(&eqn, 1u); if (e < 256) eq[e] = k; }
        }
        __syncthreads();
        if (tid == 0){
            unsigned e = eqn > 256u ? 256u : eqn;
            for (unsigned a = 1; a < e; ++a){          // tiny insertion sort (typically e<=3)
                unsigned long long kx = eq[a]; int b = (int)a - 1;
                while (b >= 0 && eq[b] > kx){ eq[b+1] = eq[b]; --b; }
                eq[b+1] = kx;
            }
            unsigned take = sremk > e ? e : sremk;
            for (unsigned r = 0; r < take; ++r) s[pos + r] = eq[r];
        }
    }
    __syncthreads();
    // bitonic sort s[1024] ascending (key = ~value | index)
    for (int k = 2; k <= KK; k <<= 1){
        for (int j = k >> 1; j > 0; j >>= 1){
            int ixj = tid ^ j;
            if (ixj > tid){
                unsigned long long a = s[tid], b = s[ixj];
                bool asc = (tid & k) == 0;
                if ((a > b) == asc){ s[tid] = b; s[ixj] = a; }
            }
            __syncthreads();
        }
    }
    unsigned long long key = s[tid];
    bool val = (key != SENT);
    unsigned int j = (unsigned int)key;
    const float* fp = f + (size_t)proj * AB;
    const float* xyz = proj ? xyz2 : xyz1;
    float4 o = make_float4(0.f, 0.f, 0.f, 0.f);
    if (val){
        o.x = xyz[(size_t)j * 3 + 0];
        o.y = xyz[(size_t)j * 3 + 1];
        o.z = xyz[(size_t)j * 3 + 2];
        o.w = fp[j];                    // radius
    }
    pr[proj * KK + tid] = o;
    vb[proj * KK + tid] = val ? 1u : 0u;
    if (proj == 1){
        int row = KK + tid;
        out[row * 3 + 0] = o.x;
        out[row * 3 + 1] = o.y;
        out[row * 3 + 2] = o.z;
        out[2 * KK * 3 + row] = o.w;                        // radius block
        out[2 * KK * 3 + 2 * KK + row] = val ? 1.0f : 0.0f; // valid block
    }
}

// ---------------- dedup (single pass, 8 blocks x 128): test 128 p1-peaks/block
// vs all 1024 p2 staged in LDS; write output rows 0..1023. Branchless.
__global__ __launch_bounds__(128) void k_dedup(const float4* __restrict__ pr,
        const unsigned int* __restrict__ vb, float* __restrict__ out){
    const float THRF = (float)(6.283185307179586 / 256.0);
    int tid = threadIdx.x;
    __shared__ float sx[KK], sy[KK], sz[KK];
    #pragma unroll
    for (int t = 0; t < 8; ++t){
        int idx = t * 128 + tid;
        float4 v = pr[KK + idx];
        bool v2 = vb[KK + idx] != 0;
        sx[idx] = v2 ? v.x : 1e9f;
        sy[idx] = v2 ? v.y : 1e9f;
        sz[idx] = v2 ? v.z : 1e9f;
    }
    __syncthreads();
    int k = blockIdx.x * 128 + tid;
    float4 m = pr[k];
    bool close = false;
    {
        #pragma clang fp contract(off)
        #pragma unroll 8
        for (int jj = 0; jj < KK; ++jj){
            float dx = m.x - sx[jj];
            float dy = m.y - sy[jj];
            float dz = m.z - sz[jj];
            float d2 = dx * dx + dy * dy + dz * dz;
            close = close | (sqrtf(d2) < THRF);
        }
    }
    bool keep = (vb[k] != 0) && !close;
    out[k * 3 + 0] = keep ? m.x : 0.0f;
    out[k * 3 + 1] = keep ? m.y : 0.0f;
    out[k * 3 + 2] = keep ? m.z : 0.0f;
    out[2 * KK * 3 + k] = keep ? m.w : 0.0f;                 // radius block
    out[2 * KK * 3 + 2 * KK + k] = keep ? 1.0f : 0.0f;       // valid block
}

extern "C" void kernel_launch(void* const* d_in, const int* in_sizes, int n_in,
                              void* d_out, int out_size, void* d_ws, size_t ws_size,
                              hipStream_t stream){
    const float* sig  = (const float*)d_in[0];
    const float* sh1  = (const float*)d_in[1];
    const float* sh2  = (const float*)d_in[2];
    const float* xyz1 = (const float*)d_in[3];
    const float* xyz2 = (const float*)d_in[4];
    float* out = (float*)d_out;
    char* ws = (char*)d_ws;

    // workspace layout (~3.2 MB)
    float* f                  = (float*)(ws);                         // 2*AB*4
    unsigned long long* cand  = (unsigned long long*)(ws + 0x100000); // 2*AB*8
    unsigned int* counts      = (unsigned int*)(ws + 0x300000);       // 8 B
    float4* pr                = (float4*)(ws + 0x310000);             // 32 KB
    unsigned int* vb          = (unsigned int*)(ws + 0x320000);       // 8 KB

    k_gemv<<<dim3(AB / 128, 2), dim3(128), 0, stream>>>(sig, sh1, sh2, f, counts);
    k_mask<<<dim3(AB / 256, 2), dim3(256), 0, stream>>>(f, cand, counts);
    k_selsort<<<dim3(1, 2), dim3(1024), 0, stream>>>(cand, counts, f, xyz1, xyz2, pr, vb, out);
    k_dedup<<<dim3(8, 1), dim3(128), 0, stream>>>(pr, vb, out);
}

// Round 12
// 195.048 us; speedup vs baseline: 1.2932x; 1.0030x over previous
//
#include <hip/hip_runtime.h>
#include <hip/hip_bf16.h>
#include <stdint.h>

#define NSH 256
#define AG 512          // alpha grid
#define BG 252          // beta grid
#define AB (AG*BG)      // 129024
#define KK 1024
#define SENT 0xFFFFFFFFFFFFFFFFull

typedef float f32x4 __attribute__((ext_vector_type(4)));
typedef __attribute__((address_space(3))) float lds_f;

// monotone float->uint map: ascending uint == ascending float
static __device__ __forceinline__ unsigned int fkey(float v){
    unsigned int u = __float_as_uint(v);
    u ^= (u >> 31) ? 0xFFFFFFFFu : 0x80000000u;
    return u;
}

#define GLOAD16(gp, lp) __builtin_amdgcn_global_load_lds( \
    (__attribute__((address_space(1))) void*)(gp), \
    (__attribute__((address_space(3))) void*)(lp), 16, 0, 0)

// ---------------- GEMV: f[j] = sum_i sig[i]*sh[i*AB+j], sequential FMA i=0..255
// Page-burst pipeline: ONE wave per block owns a 4KB row slab (1024 floats);
// per row it issues 4 contiguous global_load_lds width-16 (one 4KB DRAM burst),
// 8 rows deep (vmcnt(28), never 0). No barriers in the loop. 252 blocks.
__global__ __launch_bounds__(64) void k_gemv(const float* __restrict__ sig,
        const float* __restrict__ sh1, const float* __restrict__ sh2,
        float* __restrict__ f, unsigned int* __restrict__ counts){
    __shared__ float sig_s[NSH];
    __shared__ float tile[8][1024];           // 32 KB: 8 row slots x 4KB
    int tid = threadIdx.x;
    if (blockIdx.x == 0 && blockIdx.y == 0 && tid < 2) counts[tid] = 0;
    sig_s[tid]       = sig[tid];
    sig_s[tid + 64]  = sig[tid + 64];
    sig_s[tid + 128] = sig[tid + 128];
    sig_s[tid + 192] = sig[tid + 192];
    __syncthreads();
    int proj = blockIdx.y;
    const float* shp = proj ? sh2 : sh1;
    int jbase = blockIdx.x * 1024;
    const float* gcol = shp + jbase + tid * 4;      // per-lane src (row 0, chunk 0)
    lds_f* wrb = (lds_f*)&tile[0][0];               // wave-uniform LDS base (floats)
    lds_f* sg0 = (lds_f*)&sig_s[0];

    // prologue: rows 0..7, 4 chunk-loads each (4KB contiguous per row)
    #pragma unroll
    for (int d = 0; d < 8; ++d){
        const float* gs = gcol + (size_t)d * AB;
        GLOAD16(gs +   0, wrb + d * 1024 +   0);
        GLOAD16(gs + 256, wrb + d * 1024 + 256);
        GLOAD16(gs + 512, wrb + d * 1024 + 512);
        GLOAD16(gs + 768, wrb + d * 1024 + 768);
    }
    const float* gpf  = gcol + (size_t)8 * AB;
    const float* gmax = gcol + (size_t)(NSH - 1) * AB;   // clamp keeps vmcnt exact

    f32x4 ac0 = {0,0,0,0}, ac1 = {0,0,0,0}, ac2 = {0,0,0,0}, ac3 = {0,0,0,0};

#define GSTEP(u, sv) do{ \
        asm volatile("s_waitcnt vmcnt(28)" ::: "memory"); \
        __builtin_amdgcn_sched_barrier(0); \
        f32x4 v0, v1, v2, v3; \
        asm volatile("ds_read_b128 %0, %4\n\t" \
                     "ds_read_b128 %1, %4 offset:1024\n\t" \
                     "ds_read_b128 %2, %4 offset:2048\n\t" \
                     "ds_read_b128 %3, %4 offset:3072\n\t" \
                     "s_waitcnt lgkmcnt(0)" \
            : "=v"(v0), "=v"(v1), "=v"(v2), "=v"(v3) \
            : "v"(wrb + ((u) & 7) * 1024 + tid * 4) : "memory"); \
        ac0[0]=fmaf(sv,v0[0],ac0[0]); ac0[1]=fmaf(sv,v0[1],ac0[1]); \
        ac0[2]=fmaf(sv,v0[2],ac0[2]); ac0[3]=fmaf(sv,v0[3],ac0[3]); \
        ac1[0]=fmaf(sv,v1[0],ac1[0]); ac1[1]=fmaf(sv,v1[1],ac1[1]); \
        ac1[2]=fmaf(sv,v1[2],ac1[2]); ac1[3]=fmaf(sv,v1[3],ac1[3]); \
        ac2[0]=fmaf(sv,v2[0],ac2[0]); ac2[1]=fmaf(sv,v2[1],ac2[1]); \
        ac2[2]=fmaf(sv,v2[2],ac2[2]); ac2[3]=fmaf(sv,v2[3],ac2[3]); \
        ac3[0]=fmaf(sv,v3[0],ac3[0]); ac3[1]=fmaf(sv,v3[1],ac3[1]); \
        ac3[2]=fmaf(sv,v3[2],ac3[2]); ac3[3]=fmaf(sv,v3[3],ac3[3]); \
        const float* gs = gpf > gmax ? gmax : gpf; \
        GLOAD16(gs +   0, wrb + ((u) & 7) * 1024 +   0); \
        GLOAD16(gs + 256, wrb + ((u) & 7) * 1024 + 256); \
        GLOAD16(gs + 512, wrb + ((u) & 7) * 1024 + 512); \
        GLOAD16(gs + 768, wrb + ((u) & 7) * 1024 + 768); \
        gpf += AB; \
    }while(0)

    for (int g = 0; g < 16; ++g){
        f32x4 s0, s1, s2, s3;       // 16 sig values for this 16-row group
        asm volatile("ds_read_b128 %0, %4\n\t"
                     "ds_read_b128 %1, %4 offset:16\n\t"
                     "ds_read_b128 %2, %4 offset:32\n\t"
                     "ds_read_b128 %3, %4 offset:48\n\t"
                     "s_waitcnt lgkmcnt(0)"
            : "=v"(s0), "=v"(s1), "=v"(s2), "=v"(s3)
            : "v"(sg0 + g * 16) : "memory");
        GSTEP(0,  s0[0]); GSTEP(1,  s0[1]); GSTEP(2,  s0[2]); GSTEP(3,  s0[3]);
        GSTEP(4,  s1[0]); GSTEP(5,  s1[1]); GSTEP(6,  s1[2]); GSTEP(7,  s1[3]);
        GSTEP(8,  s2[0]); GSTEP(9,  s2[1]); GSTEP(10, s2[2]); GSTEP(11, s2[3]);
        GSTEP(12, s3[0]); GSTEP(13, s3[1]); GSTEP(14, s3[2]); GSTEP(15, s3[3]);
    }
#undef GSTEP

    asm volatile("s_waitcnt vmcnt(0)" ::: "memory");
    __builtin_amdgcn_sched_barrier(0);

    float* fo = f + (size_t)proj * AB + jbase + tid * 4;
    *reinterpret_cast<f32x4*>(fo +   0) = ac0;
    *reinterpret_cast<f32x4*>(fo + 256) = ac1;
    *reinterpret_cast<f32x4*>(fo + 512) = ac2;
    *reinterpret_cast<f32x4*>(fo + 768) = ac3;
}

// ---------------- mask + pack candidate keys (wave-aggregated atomics)
__global__ __launch_bounds__(256) void k_mask(const float* __restrict__ f,
        unsigned long long* __restrict__ cand, unsigned int* __restrict__ counts){
    int proj = blockIdx.y;
    const float* fp = f + (size_t)proj * AB;
    int j = blockIdx.x * 256 + threadIdx.x;
    bool pred = false;
    unsigned long long key = 0;
    {
        int a = j / BG, b = j - a * BG;
        if (a > 0 && a < AG - 1 && b > 0 && b < BG - 1){
            float v = fp[j];
            pred = (v > fp[j-1]) && (v > fp[j+1]) && (v > fp[j-BG]) && (v > fp[j+BG]);
            if (pred)
                key = (((unsigned long long)(~fkey(v))) << 32) | (unsigned int)j;
        }
    }
    unsigned long long bal = __ballot(pred);
    if (bal){
        int lane = threadIdx.x & 63;
        int leader = __ffsll(bal) - 1;
        unsigned int base = 0;
        if (lane == leader) base = atomicAdd(&counts[proj], (unsigned int)__popcll(bal));
        base = __shfl(base, leader);
        if (pred){
            unsigned int off = (unsigned int)__popcll(bal & ((1ull << lane) - 1ull));
            cand[(size_t)proj * AB + base + off] = key;
        }
    }
}

// ---------------- fused: radix-select (3 levels, top 24 value bits, per-wave
// privatized histograms -> no same-address atomic storms) + bitonic sort + gather.
__global__ __launch_bounds__(1024) void k_selsort(const unsigned long long* __restrict__ cand,
        const unsigned int* __restrict__ counts, const float* __restrict__ f,
        const float* __restrict__ xyz1, const float* __restrict__ xyz2,
        float4* __restrict__ pr, unsigned int* __restrict__ vb, float* __restrict__ out){
    int proj = blockIdx.y;
    const unsigned long long* cp = cand + (size_t)proj * AB;
    unsigned int count = counts[proj];
    int tid = threadIdx.x;
    __shared__ unsigned long long s[KK];          // 8 KB
    __shared__ unsigned int whist[16][256];       // 16 KB per-wave hists
    __shared__ unsigned int hist[256];            // 1 KB
    __shared__ unsigned long long eq[256];        // 2 KB
    __shared__ unsigned int sbin, sremk, pos, eqn;

    if (count <= KK){
        s[tid] = (tid < (int)count) ? cp[tid] : SENT;
    } else {
        unsigned long long prefix = 0, pmask = 0;
        unsigned int remk = KK;
        int wv = tid >> 6;
        for (int lvl = 7; lvl >= 5; --lvl){
            int shft = lvl * 8;
            for (int z = tid; z < 16 * 256; z += 1024) ((unsigned int*)whist)[z] = 0;
            __syncthreads();
            for (unsigned int i = tid; i < count; i += 1024){
                unsigned long long k = cp[i];
                if ((k & pmask) == prefix)
                    atomicAdd(&whist[wv][(unsigned int)(k >> shft) & 255u], 1u);
            }
            __syncthreads();
            if (tid < 256){
                unsigned int h = 0;
                #pragma unroll
                for (int w = 0; w < 16; ++w) h += whist[w][tid];
                hist[tid] = h;
            }
            __syncthreads();
            if (tid < 64){
                unsigned int b0 = hist[tid*4+0], b1 = hist[tid*4+1];
                unsigned int b2 = hist[tid*4+2], b3 = hist[tid*4+3];
                unsigned int lsum = b0 + b1 + b2 + b3;
                unsigned int incl = lsum;
                #pragma unroll
                for (int off = 1; off < 64; off <<= 1){
                    unsigned int v = __shfl_up(incl, off);
                    if (tid >= off) incl += v;
                }
                unsigned int excl = incl - lsum;
                if (excl < remk && remk <= incl){
                    unsigned int r = remk - excl;
                    unsigned int c0 = b0, c01 = b0 + b1, c012 = b0 + b1 + b2;
                    unsigned int bin, rr;
                    if (r <= c0){ bin = tid*4+0; rr = r; }
                    else if (r <= c01){ bin = tid*4+1; rr = r - c0; }
                    else if (r <= c012){ bin = tid*4+2; rr = r - c01; }
                    else { bin = tid*4+3; rr = r - c012; }
                    sbin = bin; sremk = rr;
                }
            }
            __syncthreads();
            prefix |= ((unsigned long long)sbin) << shft;
            pmask  |= 0xFFull << shft;
            remk = sremk;
            __syncthreads();
        }
        if (tid == 0){ pos = 0; eqn = 0; }
        __syncthreads();
        unsigned int cut24 = (unsigned int)(prefix >> 40);   // top 24 value bits
        for (unsigned int i = tid; i < count; i += 1024){
            unsigned long long k = cp[i];
            unsigned int hv = (unsigned int)(k >> 40);
            if (hv < cut24){ s[atomicAdd(&pos, 1u)] = k; }
            else if (hv == cut24){ unsigned e = atomicAdd(&eqn, 1u); if (e < 256) eq[e] = k; }
        }
        __syncthreads();
        if (tid == 0){
            unsigned e = eqn > 256u ? 256u : eqn;
            for (unsigned a = 1; a < e; ++a){
                unsigned long long kx = eq[a]; int b = (int)a - 1;
                while (b >= 0 && eq[b] > kx){ eq[b+1] = eq[b]; --b; }
                eq[b+1] = kx;
            }
            unsigned take = sremk > e ? e : sremk;
            for (unsigned r = 0; r < take; ++r) s[pos + r] = eq[r];
        }
    }
    __syncthreads();
    // bitonic sort s[1024] ascending (key = ~value | index)
    for (int k = 2; k <= KK; k <<= 1){
        for (int j = k >> 1; j > 0; j >>= 1){
            int ixj = tid ^ j;
            if (ixj > tid){
                unsigned long long a = s[tid], b = s[ixj];
                bool asc = (tid & k) == 0;
                if ((a > b) == asc){ s[tid] = b; s[ixj] = a; }
            }
            __syncthreads();
        }
    }
    unsigned long long key = s[tid];
    bool val = (key != SENT);
    unsigned int j = (unsigned int)key;
    const float* fp = f + (size_t)proj * AB;
    const float* xyz = proj ? xyz2 : xyz1;
    float4 o = make_float4(0.f, 0.f, 0.f, 0.f);
    if (val){
        o.x = xyz[(size_t)j * 3 + 0];
        o.y = xyz[(size_t)j * 3 + 1];
        o.z = xyz[(size_t)j * 3 + 2];
        o.w = fp[j];                    // radius
    }
    pr[proj * KK + tid] = o;
    vb[proj * KK + tid] = val ? 1u : 0u;
    if (proj == 1){
        int row = KK + tid;
        out[row * 3 + 0] = o.x;
        out[row * 3 + 1] = o.y;
        out[row * 3 + 2] = o.z;
        out[2 * KK * 3 + row] = o.w;                        // radius block
        out[2 * KK * 3 + 2 * KK + row] = val ? 1.0f : 0.0f; // valid block
    }
}

// ---------------- dedup (single pass, 8 blocks x 128): test 128 p1-peaks/block
// vs all 1024 p2 staged in LDS; write output rows 0..1023. Branchless.
__global__ __launch_bounds__(128) void k_dedup(const float4* __restrict__ pr,
        const unsigned int* __restrict__ vb, float* __restrict__ out){
    const float THRF = (float)(6.283185307179586 / 256.0);
    int tid = threadIdx.x;
    __shared__ float sx[KK], sy[KK], sz[KK];
    #pragma unroll
    for (int t = 0; t < 8; ++t){
        int idx = t * 128 + tid;
        float4 v = pr[KK + idx];
        bool v2 = vb[KK + idx] != 0;
        sx[idx] = v2 ? v.x : 1e9f;
        sy[idx] = v2 ? v.y : 1e9f;
        sz[idx] = v2 ? v.z : 1e9f;
    }
    __syncthreads();
    int k = blockIdx.x * 128 + tid;
    float4 m = pr[k];
    bool close = false;
    {
        #pragma clang fp contract(off)
        #pragma unroll 8
        for (int jj = 0; jj < KK; ++jj){
            float dx = m.x - sx[jj];
            float dy = m.y - sy[jj];
            float dz = m.z - sz[jj];
            float d2 = dx * dx + dy * dy + dz * dz;
            close = close | (sqrtf(d2) < THRF);
        }
    }
    bool keep = (vb[k] != 0) && !close;
    out[k * 3 + 0] = keep ? m.x : 0.0f;
    out[k * 3 + 1] = keep ? m.y : 0.0f;
    out[k * 3 + 2] = keep ? m.z : 0.0f;
    out[2 * KK * 3 + k] = keep ? m.w : 0.0f;                 // radius block
    out[2 * KK * 3 + 2 * KK + k] = keep ? 1.0f : 0.0f;       // valid block
}

extern "C" void kernel_launch(void* const* d_in, const int* in_sizes, int n_in,
                              void* d_out, int out_size, void* d_ws, size_t ws_size,
                              hipStream_t stream){
    const float* sig  = (const float*)d_in[0];
    const float* sh1  = (const float*)d_in[1];
    const float* sh2  = (const float*)d_in[2];
    const float* xyz1 = (const float*)d_in[3];
    const float* xyz2 = (const float*)d_in[4];
    float* out = (float*)d_out;
    char* ws = (char*)d_ws;

    // workspace layout (~3.2 MB)
    float* f                  = (float*)(ws);                         // 2*AB*4
    unsigned long long* cand  = (unsigned long long*)(ws + 0x100000); // 2*AB*8
    unsigned int* counts      = (unsigned int*)(ws + 0x300000);       // 8 B
    float4* pr                = (float4*)(ws + 0x310000);             // 32 KB
    unsigned int* vb          = (unsigned int*)(ws + 0x320000);       // 8 KB

    k_gemv<<<dim3(AB / 1024, 2), dim3(64), 0, stream>>>(sig, sh1, sh2, f, counts);
    k_mask<<<dim3(AB / 256, 2), dim3(256), 0, stream>>>(f, cand, counts);
    k_selsort<<<dim3(1, 2), dim3(1024), 0, stream>>>(cand, counts, f, xyz1, xyz2, pr, vb, out);
    k_dedup<<<dim3(8, 1), dim3(128), 0, stream>>>(pr, vb, out);
}